// Round 1
// baseline (326.875 us; speedup 1.0000x reference)
//
#include <hip/hip_runtime.h>

// ---------------------------------------------------------------------------
// MNIST Langevin Encoder
//   h      = relu(x @ W1^T + b1)           (16384 x 400)
//   z_loc  = h @ W21^T + b21               (16384 x 64)
//   u      = h @ W22^T + b22  (= log z_scale)
//   z0     = cache[idx]
//   25x:   z += EPS*(z_loc - z)*exp(-2u) + sqrt(2 EPS)*noise[s]
//   logq   = sum_d -0.5*((z-z_loc)*exp(-u))^2 - u - 0.5*log(2pi)
//   new_cache = cache with rows idx set to z (last write wins)
// ---------------------------------------------------------------------------

#define HID 400
#define ZD 64
#define KDIM 784
#define NSTEPS 25
#define EPSI 0.01f

// ---------------- GEMM1: h = relu(X @ W1^T + b1) ---------------------------
// X: (M,784) row-major, W1: (400,784) row-major. Tile 128x128, 8x8/thread, BK=8.
__global__ __launch_bounds__(256) void gemm1_kernel(
    const float* __restrict__ X, const float* __restrict__ W1,
    const float* __restrict__ b1, float* __restrict__ H, int M) {
  __shared__ float As[8][132];
  __shared__ float Bs[8][132];
  const int tid = threadIdx.x;
  const int m0 = blockIdx.x * 128;
  const int n0 = blockIdx.y * 128;
  const int tx = tid & 15;      // col group
  const int ty = tid >> 4;      // row group
  const int lm = tid >> 1;      // loader row 0..127
  const int kc = (tid & 1) * 4; // loader k chunk

  float acc[8][8];
#pragma unroll
  for (int i = 0; i < 8; i++)
#pragma unroll
    for (int j = 0; j < 8; j++) acc[i][j] = 0.f;

  for (int k0 = 0; k0 < KDIM; k0 += 8) {
    float4 av = *(const float4*)(X + (long)(m0 + lm) * KDIM + k0 + kc);
    float4 bv = make_float4(0.f, 0.f, 0.f, 0.f);
    const int nrow = n0 + lm;
    if (nrow < HID) bv = *(const float4*)(W1 + (long)nrow * KDIM + k0 + kc);
    __syncthreads();
    As[kc + 0][lm] = av.x; As[kc + 1][lm] = av.y;
    As[kc + 2][lm] = av.z; As[kc + 3][lm] = av.w;
    Bs[kc + 0][lm] = bv.x; Bs[kc + 1][lm] = bv.y;
    Bs[kc + 2][lm] = bv.z; Bs[kc + 3][lm] = bv.w;
    __syncthreads();
#pragma unroll
    for (int kk = 0; kk < 8; kk++) {
      float a[8], b[8];
#pragma unroll
      for (int i = 0; i < 8; i++) a[i] = As[kk][ty * 8 + i];
#pragma unroll
      for (int j = 0; j < 8; j++) b[j] = Bs[kk][tx * 8 + j];
#pragma unroll
      for (int i = 0; i < 8; i++)
#pragma unroll
        for (int j = 0; j < 8; j++) acc[i][j] += a[i] * b[j];
    }
  }

  const int colbase = n0 + tx * 8;
  if (colbase < HID) {  // HID % 8 == 0, so a thread is fully in or out
    float bb[8];
#pragma unroll
    for (int j = 0; j < 8; j++) bb[j] = b1[colbase + j];
#pragma unroll
    for (int i = 0; i < 8; i++) {
      const long ro = (long)(m0 + ty * 8 + i) * HID + colbase;
      float v[8];
#pragma unroll
      for (int j = 0; j < 8; j++) v[j] = fmaxf(acc[i][j] + bb[j], 0.f);
      *(float4*)(H + ro)     = make_float4(v[0], v[1], v[2], v[3]);
      *(float4*)(H + ro + 4) = make_float4(v[4], v[5], v[6], v[7]);
    }
  }
}

// ---------------- GEMM2: z_loc = h@W21^T+b21 ; u = h@W22^T+b22 -------------
// H: (M,400). W21/W22: (64,400). Tile 64 rows x 64 cols (full N), BK=16.
__global__ __launch_bounds__(256) void gemm2_kernel(
    const float* __restrict__ H, const float* __restrict__ W21,
    const float* __restrict__ b21, const float* __restrict__ W22,
    const float* __restrict__ b22, float* __restrict__ zloc,
    float* __restrict__ uout, int M) {
  __shared__ float Hs[16][68];
  __shared__ float Ws[2][16][68];
  const int tid = threadIdx.x;
  const int m0 = blockIdx.x * 64;
  const int tx = tid & 15;   // col group (4 cols)
  const int ty = tid >> 4;   // row group (4 rows)
  const int lr = tid >> 2;        // loader row 0..63
  const int lk = (tid & 3) * 4;   // loader k chunk

  float acc[2][4][4];
#pragma unroll
  for (int w = 0; w < 2; w++)
#pragma unroll
    for (int i = 0; i < 4; i++)
#pragma unroll
      for (int j = 0; j < 4; j++) acc[w][i][j] = 0.f;

  for (int k0 = 0; k0 < HID; k0 += 16) {
    float4 hv = *(const float4*)(H + (long)(m0 + lr) * HID + k0 + lk);
    float4 w1v = *(const float4*)(W21 + (long)lr * HID + k0 + lk);
    float4 w2v = *(const float4*)(W22 + (long)lr * HID + k0 + lk);
    __syncthreads();
    Hs[lk + 0][lr] = hv.x; Hs[lk + 1][lr] = hv.y;
    Hs[lk + 2][lr] = hv.z; Hs[lk + 3][lr] = hv.w;
    Ws[0][lk + 0][lr] = w1v.x; Ws[0][lk + 1][lr] = w1v.y;
    Ws[0][lk + 2][lr] = w1v.z; Ws[0][lk + 3][lr] = w1v.w;
    Ws[1][lk + 0][lr] = w2v.x; Ws[1][lk + 1][lr] = w2v.y;
    Ws[1][lk + 2][lr] = w2v.z; Ws[1][lk + 3][lr] = w2v.w;
    __syncthreads();
#pragma unroll
    for (int kk = 0; kk < 16; kk++) {
      float a[4], w1r[4], w2r[4];
#pragma unroll
      for (int i = 0; i < 4; i++) a[i] = Hs[kk][ty * 4 + i];
#pragma unroll
      for (int j = 0; j < 4; j++) w1r[j] = Ws[0][kk][tx * 4 + j];
#pragma unroll
      for (int j = 0; j < 4; j++) w2r[j] = Ws[1][kk][tx * 4 + j];
#pragma unroll
      for (int i = 0; i < 4; i++)
#pragma unroll
        for (int j = 0; j < 4; j++) {
          acc[0][i][j] += a[i] * w1r[j];
          acc[1][i][j] += a[i] * w2r[j];
        }
    }
  }

  const int colbase = tx * 4;
  float bl[4], bu[4];
#pragma unroll
  for (int j = 0; j < 4; j++) { bl[j] = b21[colbase + j]; bu[j] = b22[colbase + j]; }
#pragma unroll
  for (int i = 0; i < 4; i++) {
    const long ro = (long)(m0 + ty * 4 + i) * ZD + colbase;
    float zl[4], uu[4];
#pragma unroll
    for (int j = 0; j < 4; j++) {
      zl[j] = acc[0][i][j] + bl[j];
      uu[j] = acc[1][i][j] + bu[j];
    }
    *(float4*)(zloc + ro) = make_float4(zl[0], zl[1], zl[2], zl[3]);
    *(float4*)(uout + ro) = make_float4(uu[0], uu[1], uu[2], uu[3]);
  }
}

// ---------------- winner: last duplicate index wins ------------------------
__global__ void winner_kernel(const int* __restrict__ idx, int* __restrict__ winner, int B) {
  const int j = blockIdx.x * 256 + threadIdx.x;
  if (j < B) atomicMax(&winner[idx[j]], j + 1);
}

// ---------------- Langevin + logq ------------------------------------------
__global__ __launch_bounds__(256) void langevin_kernel(
    const float* __restrict__ zloc, const float* __restrict__ uarr,
    const float* __restrict__ cache, const int* __restrict__ idx,
    const float* __restrict__ noise, float* __restrict__ out_logq,
    float* __restrict__ out_z, int B) {
  const int row = blockIdx.x * 4 + (threadIdx.x >> 6);
  const int lane = threadIdx.x & 63;
  const int i = idx[row];
  const float zl = zloc[(long)row * ZD + lane];
  const float uu = uarr[(long)row * ZD + lane];
  const float a = EPSI * expf(-2.f * uu);  // EPS * inv_var
  float z = cache[(long)i * ZD + lane];
  const float coef = sqrtf(2.f * EPSI);
  const float* np = noise + (long)row * ZD + lane;
  const long stride = (long)B * ZD;
#pragma unroll
  for (int s = 0; s < NSTEPS; s++) {
    z = z + a * (zl - z) + coef * np[(long)s * stride];
  }
  out_z[(long)row * ZD + lane] = z;
  const float d = (z - zl) * expf(-uu);
  float t = -0.5f * d * d - uu - 0.91893853320467274178f;
#pragma unroll
  for (int off = 1; off < 64; off <<= 1) t += __shfl_xor(t, off);
  if (lane == 0) out_logq[row] = t;
}

// ---------------- cache copy + scatter -------------------------------------
__global__ __launch_bounds__(256) void copy_kernel(
    const float4* __restrict__ cache4, const float4* __restrict__ z4,
    const int* __restrict__ winner, float4* __restrict__ out4) {
  const long e = (long)blockIdx.x * 256 + threadIdx.x;  // element = row*16 + c
  const long row = e >> 4;
  const int c = (int)(e & 15);
  const int w = winner[row];
  float4 v;
  if (w == 0) v = cache4[e];
  else        v = z4[(long)(w - 1) * 16 + c];
  out4[e] = v;
}

extern "C" void kernel_launch(void* const* d_in, const int* in_sizes, int n_in,
                              void* d_out, int out_size, void* d_ws, size_t ws_size,
                              hipStream_t stream) {
  const float* x     = (const float*)d_in[0];
  const int*   idx   = (const int*)d_in[1];
  const float* W1    = (const float*)d_in[3];
  const float* b1    = (const float*)d_in[4];
  const float* W21   = (const float*)d_in[5];
  const float* b21   = (const float*)d_in[6];
  const float* W22   = (const float*)d_in[7];
  const float* b22   = (const float*)d_in[8];
  const float* cache = (const float*)d_in[9];
  const float* noise = (const float*)d_in[10];

  const int B = in_sizes[1];             // 16384
  const int DS = in_sizes[9] / ZD;       // 1000000

  float* out_logq  = (float*)d_out;
  float* out_z     = out_logq + B;
  float* out_cache = out_z + (long)B * ZD;

  float* h    = (float*)d_ws;                       // B*400
  float* zloc = h + (long)B * HID;                  // B*64
  float* u    = zloc + (long)B * ZD;                // B*64
  int*   win  = (int*)(u + (long)B * ZD);           // DS ints

  hipMemsetAsync(win, 0, (size_t)DS * sizeof(int), stream);

  gemm1_kernel<<<dim3(B / 128, 4), 256, 0, stream>>>(x, W1, b1, h, B);
  gemm2_kernel<<<B / 64, 256, 0, stream>>>(h, W21, b21, W22, b22, zloc, u, B);
  winner_kernel<<<(B + 255) / 256, 256, 0, stream>>>(idx, win, B);
  langevin_kernel<<<B / 4, 256, 0, stream>>>(zloc, u, cache, idx, noise,
                                             out_logq, out_z, B);
  const long total4 = (long)DS * (ZD / 4);          // 16M float4
  copy_kernel<<<(unsigned)(total4 / 256), 256, 0, stream>>>(
      (const float4*)cache, (const float4*)out_z, win, (float4*)out_cache);
}

// Round 2
// 189.378 us; speedup vs baseline: 1.7260x; 1.7260x over previous
//
#include <hip/hip_runtime.h>

// ---------------------------------------------------------------------------
// MNIST Langevin Encoder — round 2: bf16 MFMA for both GEMMs.
//   h      = relu(x @ W1^T + b1)           (16384 x 400), bf16, padded [..][512]
//   [z_loc | u] = h @ [W21;W22]^T + [b21;b22]   (16384 x 128) fp32
//   z0     = cache[idx]
//   25x:   z += EPS*(z_loc - z)*exp(-2u) + sqrt(2 EPS)*noise[s]
//   logq   = sum_d -0.5*((z-z_loc)*exp(-u))^2 - u - 0.5*log(2pi)
//   new_cache = cache with rows idx set to z (last write wins)
// LDS tiles are FRAGMENT-MAJOR (group g, lane l <-> row g*16+(l&15),
// k-chunk l>>4) so all ds_read_b128 are lane-consecutive (conflict-free),
// and global_load_lds sources are pre-permuted to match (linear LDS dest).
// ---------------------------------------------------------------------------

#define ZD 64
#define NSTEPS 25
#define EPSI 0.01f
#define K1 784
#define K1P 800
#define HSTR 512   // padded hidden stride (bf16 h)

typedef __attribute__((ext_vector_type(8))) short short8;
typedef __attribute__((ext_vector_type(4))) float f32x4;

__device__ __forceinline__ unsigned short f2bf(float f) {
  union { float f; unsigned u; } v; v.f = f;
  return (unsigned short)((v.u + 0x7FFFu + ((v.u >> 16) & 1u)) >> 16);
}

__device__ __forceinline__ void gload_lds16(const void* g, void* l) {
  __builtin_amdgcn_global_load_lds(
      (const __attribute__((address_space(1))) void*)g,
      (__attribute__((address_space(3))) void*)l, 16, 0, 0);
}

// ---------------- prep: W1 -> w1b[512][800] bf16 ; [W21;W22] -> wout[128][512]
__global__ __launch_bounds__(256) void prep_kernel(
    const float* __restrict__ W1, const float* __restrict__ W21,
    const float* __restrict__ W22, short* __restrict__ W1b,
    short* __restrict__ Wout) {
  const int t = blockIdx.x * 256 + threadIdx.x;
  const int NW1 = 512 * (K1P / 8);   // 51200 chunks of 8
  if (t < NW1) {
    const int n = t / (K1P / 8), k0 = (t % (K1P / 8)) * 8;
    short8 v = {0, 0, 0, 0, 0, 0, 0, 0};
    if (n < 400 && k0 < K1) {
      const float* s = W1 + (long)n * K1 + k0;
#pragma unroll
      for (int e = 0; e < 8; e++) v[e] = (short)f2bf(s[e]);
    }
    *(short8*)(W1b + (long)t * 8) = v;
  } else {
    const int q = t - NW1;           // wout: 128*64 = 8192 chunks
    if (q < 128 * 64) {
      const int n = q / 64, k0 = (q % 64) * 8;
      short8 v = {0, 0, 0, 0, 0, 0, 0, 0};
      if (k0 < 400) {
        const float* s = (n < 64) ? (W21 + (long)n * 400 + k0)
                                  : (W22 + (long)(n - 64) * 400 + k0);
#pragma unroll
        for (int e = 0; e < 8; e++) v[e] = (short)f2bf(s[e]);
      }
      *(short8*)(Wout + (long)q * 8) = v;
    }
  }
}

// ---------------- GEMM1: h = relu(X @ W1^T + b1), bf16 MFMA ----------------
// BM=64, BN=512 (full), BK=32, 512 threads = 8 waves (2x4), wave tile 32x128.
__global__ __launch_bounds__(512) void gemm1_kernel(
    const float* __restrict__ X, const short* __restrict__ W1b,
    const float* __restrict__ b1, unsigned short* __restrict__ H) {
  __shared__ short As[4 * 64 * 8];    // 4 KB, frag-major
  __shared__ short Bs[32 * 64 * 8];   // 32 KB, frag-major
  const int tid = threadIdx.x;
  const int w = tid >> 6;
  const int lane = tid & 63;
  const int wr = w >> 2;   // 0..1
  const int wc = w & 3;    // 0..3
  const int m0 = blockIdx.x * 64;

  const f32x4 vzero = {0.f, 0.f, 0.f, 0.f};
  f32x4 acc[2][8];
#pragma unroll
  for (int i = 0; i < 2; i++)
#pragma unroll
    for (int j = 0; j < 8; j++) acc[i][j] = vzero;

  for (int k0 = 0; k0 < K1P; k0 += 32) {
    if (k0) __syncthreads();
    // A tile (64x32): reg-stage from fp32 x with on-the-fly cvt (tid<256).
    if (tid < 256) {
      const int row = m0 + (tid >> 6) * 16 + (lane & 15);
      const int gk = k0 + (lane >> 4) * 8;
      short8 av = {0, 0, 0, 0, 0, 0, 0, 0};
      if (gk < K1) {
        const float4 f0 = *(const float4*)(X + (long)row * K1 + gk);
        const float4 f1 = *(const float4*)(X + (long)row * K1 + gk + 4);
        av[0] = (short)f2bf(f0.x); av[1] = (short)f2bf(f0.y);
        av[2] = (short)f2bf(f0.z); av[3] = (short)f2bf(f0.w);
        av[4] = (short)f2bf(f1.x); av[5] = (short)f2bf(f1.y);
        av[6] = (short)f2bf(f1.z); av[7] = (short)f2bf(f1.w);
      }
      *(short8*)(As + (long)tid * 8) = av;
    }
    // B tile (512x32): global_load_lds, 4 groups per wave.
#pragma unroll
    for (int t = 0; t < 4; t++) {
      const int gn = w * 4 + t;
      const short* src = W1b + (long)(gn * 16 + (lane & 15)) * K1P +
                         k0 + (lane >> 4) * 8;
      gload_lds16(src, Bs + gn * 512);
    }
    __syncthreads();
    const short8* Ap = (const short8*)As;
    const short8* Bp = (const short8*)Bs;
    const short8 a0 = Ap[(wr * 2 + 0) * 64 + lane];
    const short8 a1 = Ap[(wr * 2 + 1) * 64 + lane];
#pragma unroll
    for (int j = 0; j < 8; j++) {
      const short8 b = Bp[(wc * 8 + j) * 64 + lane];
      acc[0][j] = __builtin_amdgcn_mfma_f32_16x16x32_bf16(a0, b, acc[0][j], 0, 0, 0);
      acc[1][j] = __builtin_amdgcn_mfma_f32_16x16x32_bf16(a1, b, acc[1][j], 0, 0, 0);
    }
  }
  // epilogue: bias + relu + cvt -> bf16 h[row][col], stride 512
  const int colg = lane & 15;
  const int rowg = (lane >> 4) * 4;
#pragma unroll
  for (int j = 0; j < 8; j++) {
    const int col = wc * 128 + j * 16 + colg;
    const float bias = (col < 400) ? b1[col] : 0.f;
#pragma unroll
    for (int i = 0; i < 2; i++) {
      const int rbase = m0 + wr * 32 + i * 16 + rowg;
#pragma unroll
      for (int r = 0; r < 4; r++) {
        H[(long)(rbase + r) * HSTR + col] = f2bf(fmaxf(acc[i][j][r] + bias, 0.f));
      }
    }
  }
}

// ---------------- GEMM2: [zloc|u] = h @ Wout^T + b, bf16 MFMA --------------
// BM=64, BN=128 (full), BK=32, 256 threads = 4 waves (2x2), wave tile 32x64.
__global__ __launch_bounds__(256) void gemm2_kernel(
    const unsigned short* __restrict__ H, const short* __restrict__ Wout,
    const float* __restrict__ b21, const float* __restrict__ b22,
    float* __restrict__ zloc, float* __restrict__ uarr) {
  __shared__ short As[4 * 64 * 8];   // 4 KB
  __shared__ short Bs[8 * 64 * 8];   // 8 KB
  const int tid = threadIdx.x;
  const int w = tid >> 6;
  const int lane = tid & 63;
  const int wr = w >> 1;   // 0..1
  const int wc = w & 1;    // 0..1
  const int m0 = blockIdx.x * 64;

  const f32x4 vzero = {0.f, 0.f, 0.f, 0.f};
  f32x4 acc[2][4];
#pragma unroll
  for (int i = 0; i < 2; i++)
#pragma unroll
    for (int j = 0; j < 4; j++) acc[i][j] = vzero;

  for (int k0 = 0; k0 < HSTR; k0 += 32) {
    if (k0) __syncthreads();
    {  // A group g = w
      const unsigned short* src = H + (long)(m0 + w * 16 + (lane & 15)) * HSTR +
                                  k0 + (lane >> 4) * 8;
      gload_lds16(src, As + w * 512);
    }
#pragma unroll
    for (int t = 0; t < 2; t++) {  // B groups
      const int gn = w * 2 + t;
      const short* src = Wout + (long)(gn * 16 + (lane & 15)) * HSTR +
                         k0 + (lane >> 4) * 8;
      gload_lds16(src, Bs + gn * 512);
    }
    __syncthreads();
    const short8* Ap = (const short8*)As;
    const short8* Bp = (const short8*)Bs;
    const short8 a0 = Ap[(wr * 2 + 0) * 64 + lane];
    const short8 a1 = Ap[(wr * 2 + 1) * 64 + lane];
#pragma unroll
    for (int j = 0; j < 4; j++) {
      const short8 b = Bp[(wc * 4 + j) * 64 + lane];
      acc[0][j] = __builtin_amdgcn_mfma_f32_16x16x32_bf16(a0, b, acc[0][j], 0, 0, 0);
      acc[1][j] = __builtin_amdgcn_mfma_f32_16x16x32_bf16(a1, b, acc[1][j], 0, 0, 0);
    }
  }
  const int colg = lane & 15;
  const int rowg = (lane >> 4) * 4;
  float* outp = wc ? uarr : zloc;
  const float* bp = wc ? b22 : b21;
#pragma unroll
  for (int j = 0; j < 4; j++) {
    const int col = j * 16 + colg;     // 0..63 within zloc or u
    const float bias = bp[col];
#pragma unroll
    for (int i = 0; i < 2; i++) {
      const int rbase = m0 + wr * 32 + i * 16 + rowg;
#pragma unroll
      for (int r = 0; r < 4; r++) {
        outp[(long)(rbase + r) * ZD + col] = acc[i][j][r] + bias;
      }
    }
  }
}

// ---------------- winner: last duplicate index wins ------------------------
__global__ void winner_kernel(const int* __restrict__ idx, int* __restrict__ winner, int B) {
  const int j = blockIdx.x * 256 + threadIdx.x;
  if (j < B) atomicMax(&winner[idx[j]], j + 1);
}

// ---------------- Langevin + logq ------------------------------------------
__global__ __launch_bounds__(256) void langevin_kernel(
    const float* __restrict__ zloc, const float* __restrict__ uarr,
    const float* __restrict__ cache, const int* __restrict__ idx,
    const float* __restrict__ noise, float* __restrict__ out_logq,
    float* __restrict__ out_z, int B) {
  const int row = blockIdx.x * 4 + (threadIdx.x >> 6);
  const int lane = threadIdx.x & 63;
  const int i = idx[row];
  const float zl = zloc[(long)row * ZD + lane];
  const float uu = uarr[(long)row * ZD + lane];
  const float a = EPSI * expf(-2.f * uu);  // EPS * inv_var
  float z = cache[(long)i * ZD + lane];
  const float coef = sqrtf(2.f * EPSI);
  const float* np = noise + (long)row * ZD + lane;
  const long stride = (long)B * ZD;
#pragma unroll
  for (int s = 0; s < NSTEPS; s++) {
    z = z + a * (zl - z) + coef * np[(long)s * stride];
  }
  out_z[(long)row * ZD + lane] = z;
  const float d = (z - zl) * expf(-uu);
  float t = -0.5f * d * d - uu - 0.91893853320467274178f;
#pragma unroll
  for (int off = 1; off < 64; off <<= 1) t += __shfl_xor(t, off);
  if (lane == 0) out_logq[row] = t;
}

// ---------------- cache copy + scatter -------------------------------------
__global__ __launch_bounds__(256) void copy_kernel(
    const float4* __restrict__ cache4, const float4* __restrict__ z4,
    const int* __restrict__ winner, float4* __restrict__ out4) {
  const long e = (long)blockIdx.x * 256 + threadIdx.x;  // element = row*16 + c
  const long row = e >> 4;
  const int c = (int)(e & 15);
  const int w = winner[row];
  float4 v;
  if (w == 0) v = cache4[e];
  else        v = z4[(long)(w - 1) * 16 + c];
  out4[e] = v;
}

extern "C" void kernel_launch(void* const* d_in, const int* in_sizes, int n_in,
                              void* d_out, int out_size, void* d_ws, size_t ws_size,
                              hipStream_t stream) {
  const float* x     = (const float*)d_in[0];
  const int*   idx   = (const int*)d_in[1];
  const float* W1    = (const float*)d_in[3];
  const float* b1    = (const float*)d_in[4];
  const float* W21   = (const float*)d_in[5];
  const float* b21   = (const float*)d_in[6];
  const float* W22   = (const float*)d_in[7];
  const float* b22   = (const float*)d_in[8];
  const float* cache = (const float*)d_in[9];
  const float* noise = (const float*)d_in[10];

  const int B  = in_sizes[1];            // 16384
  const int DS = in_sizes[9] / ZD;       // 1000000

  float* out_logq  = (float*)d_out;
  float* out_z     = out_logq + B;
  float* out_cache = out_z + (long)B * ZD;

  // workspace layout (~30.1 MB)
  unsigned short* h = (unsigned short*)d_ws;              // B*512 bf16
  short* w1b  = (short*)(h + (long)B * HSTR);             // 512*800 bf16
  short* wout = w1b + 512 * K1P;                          // 128*512 bf16
  float* zloc = (float*)(wout + 128 * HSTR);              // B*64 f32
  float* u    = zloc + (long)B * ZD;                      // B*64 f32
  int*   win  = (int*)(u + (long)B * ZD);                 // DS ints

  hipMemsetAsync(win, 0, (size_t)DS * sizeof(int), stream);

  const int prep_chunks = 512 * (K1P / 8) + 128 * 64;
  prep_kernel<<<(prep_chunks + 255) / 256, 256, 0, stream>>>(W1, W21, W22, w1b, wout);
  gemm1_kernel<<<B / 64, 512, 0, stream>>>(x, w1b, b1, h);
  gemm2_kernel<<<B / 64, 256, 0, stream>>>(h, wout, b21, b22, zloc, u);
  winner_kernel<<<(B + 255) / 256, 256, 0, stream>>>(idx, win, B);
  langevin_kernel<<<B / 4, 256, 0, stream>>>(zloc, u, cache, idx, noise,
                                             out_logq, out_z, B);
  const long total4 = (long)DS * (ZD / 4);
  copy_kernel<<<(unsigned)(total4 / 256), 256, 0, stream>>>(
      (const float4*)cache, (const float4*)out_z, win, (float4*)out_cache);
}

// Round 3
// 187.904 us; speedup vs baseline: 1.7396x; 1.0078x over previous
//
#include <hip/hip_runtime.h>

// ---------------------------------------------------------------------------
// MNIST Langevin Encoder — round 3: drop runtime memset (custom zero kernel),
// nontemporal streaming in the cache-copy kernel.
//   h      = relu(x @ W1^T + b1)           (16384 x 400), bf16, padded [..][512]
//   [z_loc | u] = h @ [W21;W22]^T + [b21;b22]   (16384 x 128) fp32
//   z0     = cache[idx]
//   25x:   z += EPS*(z_loc - z)*exp(-2u) + sqrt(2 EPS)*noise[s]
//   logq   = sum_d -0.5*((z-z_loc)*exp(-u))^2 - u - 0.5*log(2pi)
//   new_cache = cache with rows idx set to z (last write wins)
// ---------------------------------------------------------------------------

#define ZD 64
#define NSTEPS 25
#define EPSI 0.01f
#define K1 784
#define K1P 800
#define HSTR 512   // padded hidden stride (bf16 h)

typedef __attribute__((ext_vector_type(8))) short short8;
typedef __attribute__((ext_vector_type(4))) float f32x4;
typedef __attribute__((ext_vector_type(4))) int i32x4;

__device__ __forceinline__ unsigned short f2bf(float f) {
  union { float f; unsigned u; } v; v.f = f;
  return (unsigned short)((v.u + 0x7FFFu + ((v.u >> 16) & 1u)) >> 16);
}

__device__ __forceinline__ void gload_lds16(const void* g, void* l) {
  __builtin_amdgcn_global_load_lds(
      (const __attribute__((address_space(1))) void*)g,
      (__attribute__((address_space(3))) void*)l, 16, 0, 0);
}

// ---------------- prep: W1 -> w1b[512][800] bf16 ; [W21;W22] -> wout[128][512]
__global__ __launch_bounds__(256) void prep_kernel(
    const float* __restrict__ W1, const float* __restrict__ W21,
    const float* __restrict__ W22, short* __restrict__ W1b,
    short* __restrict__ Wout) {
  const int t = blockIdx.x * 256 + threadIdx.x;
  const int NW1 = 512 * (K1P / 8);   // 51200 chunks of 8
  if (t < NW1) {
    const int n = t / (K1P / 8), k0 = (t % (K1P / 8)) * 8;
    short8 v = {0, 0, 0, 0, 0, 0, 0, 0};
    if (n < 400 && k0 < K1) {
      const float* s = W1 + (long)n * K1 + k0;
#pragma unroll
      for (int e = 0; e < 8; e++) v[e] = (short)f2bf(s[e]);
    }
    *(short8*)(W1b + (long)t * 8) = v;
  } else {
    const int q = t - NW1;           // wout: 128*64 = 8192 chunks
    if (q < 128 * 64) {
      const int n = q / 64, k0 = (q % 64) * 8;
      short8 v = {0, 0, 0, 0, 0, 0, 0, 0};
      if (k0 < 400) {
        const float* s = (n < 64) ? (W21 + (long)n * 400 + k0)
                                  : (W22 + (long)(n - 64) * 400 + k0);
#pragma unroll
        for (int e = 0; e < 8; e++) v[e] = (short)f2bf(s[e]);
      }
      *(short8*)(Wout + (long)q * 8) = v;
    }
  }
}

// ---------------- zero winner array (replaces runtime fillBuffer) ----------
__global__ __launch_bounds__(256) void zero_win_kernel(i32x4* __restrict__ win4, int n4) {
  const int t = blockIdx.x * 256 + threadIdx.x;
  if (t < n4) win4[t] = (i32x4){0, 0, 0, 0};
}

// ---------------- GEMM1: h = relu(X @ W1^T + b1), bf16 MFMA ----------------
// BM=64, BN=512 (full), BK=32, 512 threads = 8 waves (2x4), wave tile 32x128.
__global__ __launch_bounds__(512) void gemm1_kernel(
    const float* __restrict__ X, const short* __restrict__ W1b,
    const float* __restrict__ b1, unsigned short* __restrict__ H) {
  __shared__ short As[4 * 64 * 8];    // 4 KB, frag-major
  __shared__ short Bs[32 * 64 * 8];   // 32 KB, frag-major
  const int tid = threadIdx.x;
  const int w = tid >> 6;
  const int lane = tid & 63;
  const int wr = w >> 2;   // 0..1
  const int wc = w & 3;    // 0..3
  const int m0 = blockIdx.x * 64;

  const f32x4 vzero = {0.f, 0.f, 0.f, 0.f};
  f32x4 acc[2][8];
#pragma unroll
  for (int i = 0; i < 2; i++)
#pragma unroll
    for (int j = 0; j < 8; j++) acc[i][j] = vzero;

  for (int k0 = 0; k0 < K1P; k0 += 32) {
    if (k0) __syncthreads();
    // A tile (64x32): reg-stage from fp32 x with on-the-fly cvt (tid<256).
    if (tid < 256) {
      const int row = m0 + (tid >> 6) * 16 + (lane & 15);
      const int gk = k0 + (lane >> 4) * 8;
      short8 av = {0, 0, 0, 0, 0, 0, 0, 0};
      if (gk < K1) {
        const float4 f0 = *(const float4*)(X + (long)row * K1 + gk);
        const float4 f1 = *(const float4*)(X + (long)row * K1 + gk + 4);
        av[0] = (short)f2bf(f0.x); av[1] = (short)f2bf(f0.y);
        av[2] = (short)f2bf(f0.z); av[3] = (short)f2bf(f0.w);
        av[4] = (short)f2bf(f1.x); av[5] = (short)f2bf(f1.y);
        av[6] = (short)f2bf(f1.z); av[7] = (short)f2bf(f1.w);
      }
      *(short8*)(As + (long)tid * 8) = av;
    }
    // B tile (512x32): global_load_lds, 4 groups per wave.
#pragma unroll
    for (int t = 0; t < 4; t++) {
      const int gn = w * 4 + t;
      const short* src = W1b + (long)(gn * 16 + (lane & 15)) * K1P +
                         k0 + (lane >> 4) * 8;
      gload_lds16(src, Bs + gn * 512);
    }
    __syncthreads();
    const short8* Ap = (const short8*)As;
    const short8* Bp = (const short8*)Bs;
    const short8 a0 = Ap[(wr * 2 + 0) * 64 + lane];
    const short8 a1 = Ap[(wr * 2 + 1) * 64 + lane];
#pragma unroll
    for (int j = 0; j < 8; j++) {
      const short8 b = Bp[(wc * 8 + j) * 64 + lane];
      acc[0][j] = __builtin_amdgcn_mfma_f32_16x16x32_bf16(a0, b, acc[0][j], 0, 0, 0);
      acc[1][j] = __builtin_amdgcn_mfma_f32_16x16x32_bf16(a1, b, acc[1][j], 0, 0, 0);
    }
  }
  // epilogue: bias + relu + cvt -> bf16 h[row][col], stride 512
  const int colg = lane & 15;
  const int rowg = (lane >> 4) * 4;
#pragma unroll
  for (int j = 0; j < 8; j++) {
    const int col = wc * 128 + j * 16 + colg;
    const float bias = (col < 400) ? b1[col] : 0.f;
#pragma unroll
    for (int i = 0; i < 2; i++) {
      const int rbase = m0 + wr * 32 + i * 16 + rowg;
#pragma unroll
      for (int r = 0; r < 4; r++) {
        H[(long)(rbase + r) * HSTR + col] = f2bf(fmaxf(acc[i][j][r] + bias, 0.f));
      }
    }
  }
}

// ---------------- GEMM2: [zloc|u] = h @ Wout^T + b, bf16 MFMA --------------
// BM=64, BN=128 (full), BK=32, 256 threads = 4 waves (2x2), wave tile 32x64.
__global__ __launch_bounds__(256) void gemm2_kernel(
    const unsigned short* __restrict__ H, const short* __restrict__ Wout,
    const float* __restrict__ b21, const float* __restrict__ b22,
    float* __restrict__ zloc, float* __restrict__ uarr) {
  __shared__ short As[4 * 64 * 8];   // 4 KB
  __shared__ short Bs[8 * 64 * 8];   // 8 KB
  const int tid = threadIdx.x;
  const int w = tid >> 6;
  const int lane = tid & 63;
  const int wr = w >> 1;   // 0..1
  const int wc = w & 1;    // 0..1
  const int m0 = blockIdx.x * 64;

  const f32x4 vzero = {0.f, 0.f, 0.f, 0.f};
  f32x4 acc[2][4];
#pragma unroll
  for (int i = 0; i < 2; i++)
#pragma unroll
    for (int j = 0; j < 4; j++) acc[i][j] = vzero;

  for (int k0 = 0; k0 < HSTR; k0 += 32) {
    if (k0) __syncthreads();
    {  // A group g = w
      const unsigned short* src = H + (long)(m0 + w * 16 + (lane & 15)) * HSTR +
                                  k0 + (lane >> 4) * 8;
      gload_lds16(src, As + w * 512);
    }
#pragma unroll
    for (int t = 0; t < 2; t++) {  // B groups
      const int gn = w * 2 + t;
      const short* src = Wout + (long)(gn * 16 + (lane & 15)) * HSTR +
                         k0 + (lane >> 4) * 8;
      gload_lds16(src, Bs + gn * 512);
    }
    __syncthreads();
    const short8* Ap = (const short8*)As;
    const short8* Bp = (const short8*)Bs;
    const short8 a0 = Ap[(wr * 2 + 0) * 64 + lane];
    const short8 a1 = Ap[(wr * 2 + 1) * 64 + lane];
#pragma unroll
    for (int j = 0; j < 4; j++) {
      const short8 b = Bp[(wc * 4 + j) * 64 + lane];
      acc[0][j] = __builtin_amdgcn_mfma_f32_16x16x32_bf16(a0, b, acc[0][j], 0, 0, 0);
      acc[1][j] = __builtin_amdgcn_mfma_f32_16x16x32_bf16(a1, b, acc[1][j], 0, 0, 0);
    }
  }
  const int colg = lane & 15;
  const int rowg = (lane >> 4) * 4;
  float* outp = wc ? uarr : zloc;
  const float* bp = wc ? b22 : b21;
#pragma unroll
  for (int j = 0; j < 4; j++) {
    const int col = j * 16 + colg;     // 0..63 within zloc or u
    const float bias = bp[col];
#pragma unroll
    for (int i = 0; i < 2; i++) {
      const int rbase = m0 + wr * 32 + i * 16 + rowg;
#pragma unroll
      for (int r = 0; r < 4; r++) {
        outp[(long)(rbase + r) * ZD + col] = acc[i][j][r] + bias;
      }
    }
  }
}

// ---------------- winner: last duplicate index wins ------------------------
__global__ void winner_kernel(const int* __restrict__ idx, int* __restrict__ winner, int B) {
  const int j = blockIdx.x * 256 + threadIdx.x;
  if (j < B) atomicMax(&winner[idx[j]], j + 1);
}

// ---------------- Langevin + logq ------------------------------------------
__global__ __launch_bounds__(256) void langevin_kernel(
    const float* __restrict__ zloc, const float* __restrict__ uarr,
    const float* __restrict__ cache, const int* __restrict__ idx,
    const float* __restrict__ noise, float* __restrict__ out_logq,
    float* __restrict__ out_z, int B) {
  const int row = blockIdx.x * 4 + (threadIdx.x >> 6);
  const int lane = threadIdx.x & 63;
  const int i = idx[row];
  const float zl = zloc[(long)row * ZD + lane];
  const float uu = uarr[(long)row * ZD + lane];
  const float a = EPSI * expf(-2.f * uu);  // EPS * inv_var
  float z = cache[(long)i * ZD + lane];
  const float coef = sqrtf(2.f * EPSI);
  const float* np = noise + (long)row * ZD + lane;
  const long stride = (long)B * ZD;
#pragma unroll
  for (int s = 0; s < NSTEPS; s++) {
    z = z + a * (zl - z) + coef * np[(long)s * stride];
  }
  out_z[(long)row * ZD + lane] = z;
  const float d = (z - zl) * expf(-uu);
  float t = -0.5f * d * d - uu - 0.91893853320467274178f;
#pragma unroll
  for (int off = 1; off < 64; off <<= 1) t += __shfl_xor(t, off);
  if (lane == 0) out_logq[row] = t;
}

// ---------------- cache copy + scatter (nontemporal streaming) -------------
__global__ __launch_bounds__(256) void copy_kernel(
    const f32x4* __restrict__ cache4, const f32x4* __restrict__ z4,
    const int* __restrict__ winner, f32x4* __restrict__ out4) {
  const long e = (long)blockIdx.x * 256 + threadIdx.x;  // element = row*16 + c
  const long row = e >> 4;
  const int c = (int)(e & 15);
  const int w = winner[row];
  f32x4 v;
  if (w == 0) v = __builtin_nontemporal_load(&cache4[e]);
  else        v = z4[(long)(w - 1) * 16 + c];
  __builtin_nontemporal_store(v, &out4[e]);
}

extern "C" void kernel_launch(void* const* d_in, const int* in_sizes, int n_in,
                              void* d_out, int out_size, void* d_ws, size_t ws_size,
                              hipStream_t stream) {
  const float* x     = (const float*)d_in[0];
  const int*   idx   = (const int*)d_in[1];
  const float* W1    = (const float*)d_in[3];
  const float* b1    = (const float*)d_in[4];
  const float* W21   = (const float*)d_in[5];
  const float* b21   = (const float*)d_in[6];
  const float* W22   = (const float*)d_in[7];
  const float* b22   = (const float*)d_in[8];
  const float* cache = (const float*)d_in[9];
  const float* noise = (const float*)d_in[10];

  const int B  = in_sizes[1];            // 16384
  const int DS = in_sizes[9] / ZD;       // 1000000

  float* out_logq  = (float*)d_out;
  float* out_z     = out_logq + B;
  float* out_cache = out_z + (long)B * ZD;

  // workspace layout (~30.1 MB)
  unsigned short* h = (unsigned short*)d_ws;              // B*512 bf16
  short* w1b  = (short*)(h + (long)B * HSTR);             // 512*800 bf16
  short* wout = w1b + 512 * K1P;                          // 128*512 bf16
  float* zloc = (float*)(wout + 128 * HSTR);              // B*64 f32
  float* u    = zloc + (long)B * ZD;                      // B*64 f32
  int*   win  = (int*)(u + (long)B * ZD);                 // DS ints

  const int n4 = (DS + 3) / 4;                            // 250000 int4
  zero_win_kernel<<<(n4 + 255) / 256, 256, 0, stream>>>((i32x4*)win, n4);

  const int prep_chunks = 512 * (K1P / 8) + 128 * 64;
  prep_kernel<<<(prep_chunks + 255) / 256, 256, 0, stream>>>(W1, W21, W22, w1b, wout);
  gemm1_kernel<<<B / 64, 512, 0, stream>>>(x, w1b, b1, h);
  gemm2_kernel<<<B / 64, 256, 0, stream>>>(h, wout, b21, b22, zloc, u);
  winner_kernel<<<(B + 255) / 256, 256, 0, stream>>>(idx, win, B);
  langevin_kernel<<<B / 4, 256, 0, stream>>>(zloc, u, cache, idx, noise,
                                             out_logq, out_z, B);
  const long total4 = (long)DS * (ZD / 4);
  copy_kernel<<<(unsigned)(total4 / 256), 256, 0, stream>>>(
      (const f32x4*)cache, (const f32x4*)out_z, win, (f32x4*)out_cache);
}